// Round 1
// baseline (7515.550 us; speedup 1.0000x reference)
//
#include <hip/hip_runtime.h>
#include <hip/hip_bf16.h>

#define S 2048
#define HD 512
#define EDIM 512
#define NT 12
#define G4 2048            // 4*HD gate rows
#define NWG 16             // workgroups per direction
#define JPW 32             // hidden units per WG (HD/NWG)
#define ROWS 128           // gate rows per WG (4*JPW)
#define WSTRIDE 520        // padded LDS row stride in bf16 elems (1040B, 16B aligned, banks spread)

typedef unsigned short ushort_t;
typedef unsigned int uint_t;

__device__ __forceinline__ ushort_t f2b(float f) {
    uint_t u = __float_as_uint(f);
    uint_t r = u + 0x7fffu + ((u >> 16) & 1u);
    return (ushort_t)(r >> 16);
}
__device__ __forceinline__ float b2f(ushort_t h) {
    return __uint_as_float(((uint_t)h) << 16);
}
__device__ __forceinline__ float sigm(float x) { return 1.f / (1.f + __expf(-x)); }
__device__ __forceinline__ float tanh_(float x) {
    float e = __expf(2.f * x);
    return 1.f - 2.f / (e + 1.f);
}

// ---------------- whh f32 -> bf16 conversion ----------------
__global__ void conv_whh(const float* __restrict__ a, const float* __restrict__ b,
                         ushort_t* __restrict__ o) {
    int i = blockIdx.x * 256 + threadIdx.x;        // 524288 threads, 4 elems each
    const float* src = (i < 262144) ? (a + (size_t)i * 4) : (b + (size_t)(i - 262144) * 4);
    float4 v = *(const float4*)src;
    ushort4 u;
    u.x = f2b(v.x); u.y = f2b(v.y); u.z = f2b(v.z); u.w = f2b(v.w);
    *(ushort4*)(o + (size_t)i * 4) = u;
}

// ---------------- xw GEMM: xw[d][t][r] = emb[tok(d,t)] . wih_d[r] + b_d[r] ----------------
__global__ __launch_bounds__(256, 2)
void xw_gemm(const int* __restrict__ sentence, const float* __restrict__ emb,
             const float* __restrict__ wih_f, const float* __restrict__ b_f,
             const float* __restrict__ wih_b, const float* __restrict__ b_b,
             ushort_t* __restrict__ xw) {
    __shared__ float As[32][68];
    __shared__ float Bs[32][68];
    __shared__ int toks[64];
    const int tid = threadIdx.x;
    const int tbase = blockIdx.x * 64;
    const int rbase = blockIdx.y * 64;
    const int dir = blockIdx.z;
    const float* wih = dir ? wih_b : wih_f;
    const float* bia = dir ? b_b : b_f;
    if (tid < 64) {
        int tt = tbase + tid;
        toks[tid] = sentence[dir ? (S - 1 - tt) : tt];
    }
    __syncthreads();
    const int lm = tid >> 2;
    const int lk = (tid & 3) * 8;
    const int ty = tid >> 4, tx = tid & 15;
    const float* aBase = emb + (size_t)toks[lm] * EDIM + lk;
    const float* bBase = wih + (size_t)(rbase + lm) * EDIM + lk;
    float acc[4][4];
#pragma unroll
    for (int i = 0; i < 4; ++i)
#pragma unroll
        for (int j = 0; j < 4; ++j) acc[i][j] = 0.f;

    for (int kc = 0; kc < EDIM; kc += 32) {
        float4 a0 = ((const float4*)(aBase + kc))[0];
        float4 a1 = ((const float4*)(aBase + kc))[1];
        float4 b0 = ((const float4*)(bBase + kc))[0];
        float4 b1 = ((const float4*)(bBase + kc))[1];
        __syncthreads();
        As[lk + 0][lm] = a0.x; As[lk + 1][lm] = a0.y; As[lk + 2][lm] = a0.z; As[lk + 3][lm] = a0.w;
        As[lk + 4][lm] = a1.x; As[lk + 5][lm] = a1.y; As[lk + 6][lm] = a1.z; As[lk + 7][lm] = a1.w;
        Bs[lk + 0][lm] = b0.x; Bs[lk + 1][lm] = b0.y; Bs[lk + 2][lm] = b0.z; Bs[lk + 3][lm] = b0.w;
        Bs[lk + 4][lm] = b1.x; Bs[lk + 5][lm] = b1.y; Bs[lk + 6][lm] = b1.z; Bs[lk + 7][lm] = b1.w;
        __syncthreads();
#pragma unroll
        for (int kk = 0; kk < 32; ++kk) {
            float4 a4 = *(const float4*)&As[kk][ty * 4];
            float4 b4 = *(const float4*)&Bs[kk][tx * 4];
            float av[4] = {a4.x, a4.y, a4.z, a4.w};
            float bv[4] = {b4.x, b4.y, b4.z, b4.w};
#pragma unroll
            for (int i = 0; i < 4; ++i)
#pragma unroll
                for (int j = 0; j < 4; ++j) acc[i][j] = fmaf(av[i], bv[j], acc[i][j]);
        }
    }
    float4 bi = *(const float4*)&bia[rbase + tx * 4];
    float bvv[4] = {bi.x, bi.y, bi.z, bi.w};
#pragma unroll
    for (int i = 0; i < 4; ++i) {
        ushort4 o;
        o.x = f2b(acc[i][0] + bvv[0]);
        o.y = f2b(acc[i][1] + bvv[1]);
        o.z = f2b(acc[i][2] + bvv[2]);
        o.w = f2b(acc[i][3] + bvv[3]);
        ushort_t* p = xw + ((size_t)dir * S + tbase + ty * 4 + i) * G4 + rbase + tx * 4;
        *(ushort4*)p = o;
    }
}

// ---------------- LSTM recurrence: 32 WGs (16 per dir), spin-sync via NaN canary ----------------
__global__ __launch_bounds__(256, 1)
void lstm_rec(const ushort_t* __restrict__ whh16, const float* __restrict__ h0,
              const float* __restrict__ c0, const ushort_t* __restrict__ xw,
              float* hs) {
    extern __shared__ ushort_t wlds[];     // ROWS * WSTRIDE bf16
    __shared__ ushort_t hstage[HD];        // staged h (bf16)
    __shared__ float gates[ROWS];
    const int tid = threadIdx.x;
    const int dir = blockIdx.x >> 4;
    const int wg = blockIdx.x & 15;
    const int jbase = wg * JPW;
    const int rho = tid >> 1, half = tid & 1;
    const int g = rho >> 5, jj = rho & 31;
    const int grow = g * HD + jbase + jj;  // global gate row

    // load bf16 weight slice into LDS: row rho holds whh[grow][:]
    {
        const ushort_t* wsrc = whh16 + ((size_t)dir * G4 + grow) * HD + half * 256;
        ushort_t* wdst = wlds + rho * WSTRIDE + half * 256;
#pragma unroll
        for (int i = 0; i < 32; ++i) ((uint4*)wdst)[i] = ((const uint4*)wsrc)[i];
    }

    const ushort_t* xwd = xw + (size_t)dir * S * G4;
    float* hsd = hs + (size_t)dir * S * HD;

    float cj = 0.f;
    if (tid < JPW) cj = c0[dir * HD + jbase + tid];

    // stage h0
    hstage[2 * tid] = f2b(h0[dir * HD + 2 * tid]);
    hstage[2 * tid + 1] = f2b(h0[dir * HD + 2 * tid + 1]);
    __syncthreads();

    const uint4* wp = (const uint4*)(wlds + rho * WSTRIDE + half * 256);

    for (int t = 0; t < S; ++t) {
        ushort_t xr = xwd[(size_t)t * G4 + grow];   // prefetch (used by even lanes)
        const uint4* hp = (const uint4*)(hstage + half * 256);
        float acc = 0.f;
#pragma unroll
        for (int i = 0; i < 32; ++i) {
            uint4 w4 = wp[i];
            uint4 h4 = hp[i];
            acc = fmaf(__uint_as_float(w4.x << 16), __uint_as_float(h4.x << 16), acc);
            acc = fmaf(__uint_as_float(w4.x & 0xffff0000u), __uint_as_float(h4.x & 0xffff0000u), acc);
            acc = fmaf(__uint_as_float(w4.y << 16), __uint_as_float(h4.y << 16), acc);
            acc = fmaf(__uint_as_float(w4.y & 0xffff0000u), __uint_as_float(h4.y & 0xffff0000u), acc);
            acc = fmaf(__uint_as_float(w4.z << 16), __uint_as_float(h4.z << 16), acc);
            acc = fmaf(__uint_as_float(w4.z & 0xffff0000u), __uint_as_float(h4.z & 0xffff0000u), acc);
            acc = fmaf(__uint_as_float(w4.w << 16), __uint_as_float(h4.w << 16), acc);
            acc = fmaf(__uint_as_float(w4.w & 0xffff0000u), __uint_as_float(h4.w & 0xffff0000u), acc);
        }
        acc += __shfl_xor(acc, 1);
        if (half == 0) gates[rho] = acc + b2f(xr);
        __syncthreads();                                   // SYNC A
        if (tid < JPW) {
            float ai = gates[tid], af = gates[JPW + tid];
            float ag = gates[2 * JPW + tid], ao = gates[3 * JPW + tid];
            float ii = sigm(ai), ff = sigm(af), gg = tanh_(ag), oo = sigm(ao);
            cj = ff * cj + ii * gg;
            float hnew = oo * tanh_(cj);
            __hip_atomic_store(&hsd[(size_t)t * HD + jbase + tid], hnew,
                               __ATOMIC_RELAXED, __HIP_MEMORY_SCOPE_AGENT);
        }
        if (t < S - 1) {
            float* p0 = &hsd[(size_t)t * HD + 2 * tid];
            float v0, v1;
            for (;;) {
                v0 = __hip_atomic_load(&p0[0], __ATOMIC_RELAXED, __HIP_MEMORY_SCOPE_AGENT);
                v1 = __hip_atomic_load(&p0[1], __ATOMIC_RELAXED, __HIP_MEMORY_SCOPE_AGENT);
                if (__float_as_uint(v0) != 0xFFFFFFFFu && __float_as_uint(v1) != 0xFFFFFFFFu) break;
                __builtin_amdgcn_s_sleep(1);
            }
            hstage[2 * tid] = f2b(v0);
            hstage[2 * tid + 1] = f2b(v1);
        }
        __syncthreads();                                   // SYNC B
    }
}

// ---------------- feats: [S][12] = concat(hf, hb_rev) @ w_out.T + b_out ----------------
__global__ __launch_bounds__(256)
void feats_k(const float* __restrict__ hs, const float* __restrict__ w_out,
             const float* __restrict__ b_out, float* __restrict__ feats) {
    const int t = blockIdx.x, tid = threadIdx.x;
    float4 h4;
    if (tid < 128)
        h4 = *(const float4*)&hs[(size_t)t * HD + tid * 4];
    else
        h4 = *(const float4*)&hs[(size_t)S * HD + (size_t)(S - 1 - t) * HD + (tid - 128) * 4];
    float acc[NT];
#pragma unroll
    for (int tg = 0; tg < NT; ++tg) {
        float4 w4 = *(const float4*)&w_out[(size_t)tg * 1024 + tid * 4];
        acc[tg] = h4.x * w4.x + h4.y * w4.y + h4.z * w4.z + h4.w * w4.w;
    }
#pragma unroll
    for (int m = 1; m < 64; m <<= 1)
#pragma unroll
        for (int tg = 0; tg < NT; ++tg) acc[tg] += __shfl_xor(acc[tg], m);
    __shared__ float part[4][NT];
    if ((tid & 63) == 0) {
#pragma unroll
        for (int tg = 0; tg < NT; ++tg) part[tid >> 6][tg] = acc[tg];
    }
    __syncthreads();
    if (tid < NT)
        feats[(size_t)t * NT + tid] =
            part[0][tid] + part[1][tid] + part[2][tid] + part[3][tid] + b_out[tid];
}

// ---------------- CRF: forward algorithm + gold score, single block ----------------
__global__ __launch_bounds__(256, 1)
void crf_k(const float* __restrict__ feats, const int* __restrict__ gold,
           const float* __restrict__ trans, float* __restrict__ out) {
    extern __shared__ float sfeats[];      // S*NT floats = 96KB
    __shared__ float red[256];
    __shared__ float nprev[NT];
    __shared__ float tr[144];
    __shared__ float gold_sh;
    const int tid = threadIdx.x;
    for (int i = tid; i < S * NT / 4; i += 256)
        ((float4*)sfeats)[i] = ((const float4*)feats)[i];
    if (tid < 144) tr[tid] = trans[tid];
    __syncthreads();
    // gold score
    float gsum = 0.f;
    for (int t = tid; t < S; t += 256) {
        int a = gold[t];
        int b = t ? gold[t - 1] : 0;
        gsum += tr[a * NT + b] + sfeats[t * NT + a];
    }
    red[tid] = gsum;
    __syncthreads();
    for (int s = 128; s; s >>= 1) {
        if (tid < s) red[tid] += red[tid + s];
        __syncthreads();
    }
    if (tid == 0) gold_sh = red[0] + tr[1 * NT + gold[S - 1]];
    __syncthreads();
    // forward algorithm: i = tid/16 (next tag), j = tid%16 (prev tag)
    const int i = tid >> 4, j = tid & 15;
    const bool act = (tid < 192) && (j < NT);
    float tij = act ? tr[i * NT + j] : -3e38f;
    float prev = (j == 0) ? 0.f : -1e6f;
    for (int t = 0; t < S; ++t) {
        float v = act ? (prev + tij) : -3e38f;
        float mx = v;
        mx = fmaxf(mx, __shfl_xor(mx, 1));
        mx = fmaxf(mx, __shfl_xor(mx, 2));
        mx = fmaxf(mx, __shfl_xor(mx, 4));
        mx = fmaxf(mx, __shfl_xor(mx, 8));
        float e = __expf(v - mx);
        float ss = e;
        ss += __shfl_xor(ss, 1);
        ss += __shfl_xor(ss, 2);
        ss += __shfl_xor(ss, 4);
        ss += __shfl_xor(ss, 8);
        if (tid < 192 && j == 0) nprev[i] = mx + __logf(ss) + sfeats[t * NT + i];
        __syncthreads();
        prev = nprev[j < NT ? j : 0];
        __syncthreads();
    }
    if (tid < 64) {
        float v2 = (tid < NT) ? prev + tr[1 * NT + tid] : -3e38f;
        float mx = v2;
        mx = fmaxf(mx, __shfl_xor(mx, 1));
        mx = fmaxf(mx, __shfl_xor(mx, 2));
        mx = fmaxf(mx, __shfl_xor(mx, 4));
        mx = fmaxf(mx, __shfl_xor(mx, 8));
        float e = __expf(v2 - mx);
        float ss = e;
        ss += __shfl_xor(ss, 1);
        ss += __shfl_xor(ss, 2);
        ss += __shfl_xor(ss, 4);
        ss += __shfl_xor(ss, 8);
        if (tid == 0) out[0] = (mx + __logf(ss)) - gold_sh;
    }
}

extern "C" void kernel_launch(void* const* d_in, const int* in_sizes, int n_in,
                              void* d_out, int out_size, void* d_ws, size_t ws_size,
                              hipStream_t stream) {
    const int* sentence = (const int*)d_in[0];
    const int* gold = (const int*)d_in[1];
    const float* emb = (const float*)d_in[2];
    const float* wih_f = (const float*)d_in[3];
    const float* whh_f = (const float*)d_in[4];
    const float* b_f = (const float*)d_in[5];
    const float* wih_b = (const float*)d_in[6];
    const float* whh_b = (const float*)d_in[7];
    const float* b_b = (const float*)d_in[8];
    const float* w_out = (const float*)d_in[9];
    const float* b_out = (const float*)d_in[10];
    const float* trans = (const float*)d_in[11];
    const float* h0 = (const float*)d_in[12];
    const float* c0 = (const float*)d_in[13];
    float* out = (float*)d_out;

    char* ws = (char*)d_ws;
    const size_t XW_B = (size_t)2 * S * G4 * 2;          // 16,777,216
    const size_t HS_B = (size_t)2 * S * HD * 4;          // 8,388,608
    const size_t WH_B = (size_t)2 * G4 * HD * 2;         // 4,194,304
    ushort_t* xw = (ushort_t*)ws;
    float* hs = (float*)(ws + XW_B);
    ushort_t* whh16 = (ushort_t*)(ws + XW_B + HS_B);
    float* feats = (float*)(ws + XW_B + HS_B + WH_B);

    // canary-fill h state buffers (0xFFFFFFFF = NaN, impossible output value)
    hipMemsetAsync(hs, 0xFF, HS_B, stream);

    conv_whh<<<2048, 256, 0, stream>>>(whh_f, whh_b, whh16);

    dim3 gg(S / 64, G4 / 64, 2);
    xw_gemm<<<gg, 256, 0, stream>>>(sentence, emb, wih_f, b_f, wih_b, b_b, xw);

    static const size_t REC_LDS = (size_t)ROWS * WSTRIDE * 2;   // 133,120 B
    hipFuncSetAttribute((const void*)lstm_rec,
                        hipFuncAttributeMaxDynamicSharedMemorySize, (int)REC_LDS);
    lstm_rec<<<2 * NWG, 256, REC_LDS, stream>>>(whh16, h0, c0, xw, hs);

    feats_k<<<S, 256, 0, stream>>>(hs, w_out, b_out, feats);

    const size_t CRF_LDS = (size_t)S * NT * 4;                  // 98,304 B
    hipFuncSetAttribute((const void*)crf_k,
                        hipFuncAttributeMaxDynamicSharedMemorySize, (int)CRF_LDS);
    crf_k<<<1, 256, CRF_LDS, stream>>>(feats, gold, trans, out);
}

// Round 2
// 5393.447 us; speedup vs baseline: 1.3935x; 1.3935x over previous
//
#include <hip/hip_runtime.h>
#include <hip/hip_bf16.h>

#define S 2048
#define HD 512
#define EDIM 512
#define NT 12
#define G4 2048            // 4*HD gate rows
#define NWGD 64            // workgroups per direction
#define RPW 32             // gate rows per WG (4 gates x JPW)
#define JPW 8              // hidden units per WG (HD/NWGD)
#define HSTR 36            // hstage chunk stride in dwords (16B aligned, 2-way banks = free)

typedef unsigned short ushort_t;
typedef unsigned int uint_t;

__device__ __forceinline__ ushort_t f2b(float f) {
    uint_t u = __float_as_uint(f);
    uint_t r = u + 0x7fffu + ((u >> 16) & 1u);
    return (ushort_t)(r >> 16);
}
__device__ __forceinline__ float b2f(ushort_t h) {
    return __uint_as_float(((uint_t)h) << 16);
}
__device__ __forceinline__ float sigm(float x) { return 1.f / (1.f + __expf(-x)); }
__device__ __forceinline__ float tanh_(float x) {
    float e = __expf(2.f * x);
    return 1.f - 2.f / (e + 1.f);
}

// ---------------- xw GEMM: xw[d][t][r] = emb[tok(d,t)] . wih_d[r] + b_d[r] ----------------
__global__ __launch_bounds__(256, 2)
void xw_gemm(const int* __restrict__ sentence, const float* __restrict__ emb,
             const float* __restrict__ wih_f, const float* __restrict__ b_f,
             const float* __restrict__ wih_b, const float* __restrict__ b_b,
             ushort_t* __restrict__ xw) {
    __shared__ float As[32][68];
    __shared__ float Bs[32][68];
    __shared__ int toks[64];
    const int tid = threadIdx.x;
    const int tbase = blockIdx.x * 64;
    const int rbase = blockIdx.y * 64;
    const int dir = blockIdx.z;
    const float* wih = dir ? wih_b : wih_f;
    const float* bia = dir ? b_b : b_f;
    if (tid < 64) {
        int tt = tbase + tid;
        toks[tid] = sentence[dir ? (S - 1 - tt) : tt];
    }
    __syncthreads();
    const int lm = tid >> 2;
    const int lk = (tid & 3) * 8;
    const int ty = tid >> 4, tx = tid & 15;
    const float* aBase = emb + (size_t)toks[lm] * EDIM + lk;
    const float* bBase = wih + (size_t)(rbase + lm) * EDIM + lk;
    float acc[4][4];
#pragma unroll
    for (int i = 0; i < 4; ++i)
#pragma unroll
        for (int j = 0; j < 4; ++j) acc[i][j] = 0.f;

    for (int kc = 0; kc < EDIM; kc += 32) {
        float4 a0 = ((const float4*)(aBase + kc))[0];
        float4 a1 = ((const float4*)(aBase + kc))[1];
        float4 b0 = ((const float4*)(bBase + kc))[0];
        float4 b1 = ((const float4*)(bBase + kc))[1];
        __syncthreads();
        As[lk + 0][lm] = a0.x; As[lk + 1][lm] = a0.y; As[lk + 2][lm] = a0.z; As[lk + 3][lm] = a0.w;
        As[lk + 4][lm] = a1.x; As[lk + 5][lm] = a1.y; As[lk + 6][lm] = a1.z; As[lk + 7][lm] = a1.w;
        Bs[lk + 0][lm] = b0.x; Bs[lk + 1][lm] = b0.y; Bs[lk + 2][lm] = b0.z; Bs[lk + 3][lm] = b0.w;
        Bs[lk + 4][lm] = b1.x; Bs[lk + 5][lm] = b1.y; Bs[lk + 6][lm] = b1.z; Bs[lk + 7][lm] = b1.w;
        __syncthreads();
#pragma unroll
        for (int kk = 0; kk < 32; ++kk) {
            float4 a4 = *(const float4*)&As[kk][ty * 4];
            float4 b4 = *(const float4*)&Bs[kk][tx * 4];
            float av[4] = {a4.x, a4.y, a4.z, a4.w};
            float bv[4] = {b4.x, b4.y, b4.z, b4.w};
#pragma unroll
            for (int i = 0; i < 4; ++i)
#pragma unroll
                for (int j = 0; j < 4; ++j) acc[i][j] = fmaf(av[i], bv[j], acc[i][j]);
        }
    }
    float4 bi = *(const float4*)&bia[rbase + tx * 4];
    float bvv[4] = {bi.x, bi.y, bi.z, bi.w};
#pragma unroll
    for (int i = 0; i < 4; ++i) {
        ushort4 o;
        o.x = f2b(acc[i][0] + bvv[0]);
        o.y = f2b(acc[i][1] + bvv[1]);
        o.z = f2b(acc[i][2] + bvv[2]);
        o.w = f2b(acc[i][3] + bvv[3]);
        ushort_t* p = xw + ((size_t)dir * S + tbase + ty * 4 + i) * G4 + rbase + tx * 4;
        *(ushort4*)p = o;
    }
}

// ---------------- LSTM recurrence: 128 WGs (64/dir), register-stationary f32 weights ----------------
// Lane layout: rg = tid>>4 (16 row-groups of 2 rows), kc = tid&15 (16 k-chunks of 32).
// Each lane holds w[2 rows][32 k] in VGPRs (64 f32). h staged in padded LDS (broadcast reads).
__global__ __launch_bounds__(256, 1)
void lstm_rec(const float* __restrict__ whh_f, const float* __restrict__ whh_b,
              const float* __restrict__ h0, const float* __restrict__ c0,
              const ushort_t* __restrict__ xw, float* hs) {
    __shared__ float hstage[16 * HSTR];    // padded: chunk c at dword c*36 -> 2-way banks (free)
    __shared__ float gates[RPW];
    const int tid = threadIdx.x;
    const int dir = blockIdx.x >> 6;
    const int wg = blockIdx.x & 63;
    const int jbase = wg * JPW;
    const int rg = tid >> 4, kc = tid & 15;
    const float* whh = dir ? whh_b : whh_f;

    int grow[2];
#pragma unroll
    for (int ri = 0; ri < 2; ++ri) {
        int r = rg * 2 + ri;                       // local row in [0,32)
        grow[ri] = (r >> 3) * HD + jbase + (r & 7); // global gate row
    }
    // register-stationary weights: 2 rows x 32 k = 16 float4
    float4 w[2][8];
#pragma unroll
    for (int ri = 0; ri < 2; ++ri)
#pragma unroll
        for (int i = 0; i < 8; ++i)
            w[ri][i] = *(const float4*)&whh[(size_t)grow[ri] * HD + kc * 32 + i * 4];

    const ushort_t* xwd = xw + (size_t)dir * S * G4;
    float* hsd = hs + (size_t)dir * S * HD;

    float cj = 0.f;
    if (tid < JPW) cj = c0[dir * HD + jbase + tid];

    // stage h0 (f32, padded layout)
    {
        int c = tid >> 4, m = (2 * tid) & 31;
        hstage[c * HSTR + m] = h0[dir * HD + 2 * tid];
        hstage[c * HSTR + m + 1] = h0[dir * HD + 2 * tid + 1];
    }
    __syncthreads();

    const bool isw = (kc == 0);
    for (int t = 0; t < S; ++t) {
        float xv0 = 0.f, xv1 = 0.f;
        if (isw) {                                   // prefetch xw early, consumed post-reduce
            xv0 = b2f(xwd[(size_t)t * G4 + grow[0]]);
            xv1 = b2f(xwd[(size_t)t * G4 + grow[1]]);
        }
        float a0 = 0.f, a1 = 0.f;
#pragma unroll
        for (int i = 0; i < 8; ++i) {
            float4 h4 = *(const float4*)&hstage[kc * HSTR + i * 4];
            a0 = fmaf(w[0][i].x, h4.x, a0); a0 = fmaf(w[0][i].y, h4.y, a0);
            a0 = fmaf(w[0][i].z, h4.z, a0); a0 = fmaf(w[0][i].w, h4.w, a0);
            a1 = fmaf(w[1][i].x, h4.x, a1); a1 = fmaf(w[1][i].y, h4.y, a1);
            a1 = fmaf(w[1][i].z, h4.z, a1); a1 = fmaf(w[1][i].w, h4.w, a1);
        }
#pragma unroll
        for (int m = 1; m < 16; m <<= 1) {
            a0 += __shfl_xor(a0, m);
            a1 += __shfl_xor(a1, m);
        }
        if (isw) {
            gates[rg * 2] = a0 + xv0;
            gates[rg * 2 + 1] = a1 + xv1;
        }
        __syncthreads();                             // SYNC A
        if (tid < JPW) {
            float ai = gates[tid], af = gates[JPW + tid];
            float ag = gates[2 * JPW + tid], ao = gates[3 * JPW + tid];
            float ii = sigm(ai), ff = sigm(af), gg = tanh_(ag), oo = sigm(ao);
            cj = ff * cj + ii * gg;
            float hnew = oo * tanh_(cj);
            __hip_atomic_store(&hsd[(size_t)t * HD + jbase + tid], hnew,
                               __ATOMIC_RELAXED, __HIP_MEMORY_SCOPE_AGENT);
        }
        if (t < S - 1) {
            const unsigned long long* p0 =
                (const unsigned long long*)&hsd[(size_t)t * HD + 2 * tid];
            float v0, v1;
            for (;;) {
                unsigned long long v =
                    __hip_atomic_load(p0, __ATOMIC_RELAXED, __HIP_MEMORY_SCOPE_AGENT);
                uint_t lo = (uint_t)v, hi = (uint_t)(v >> 32);
                if (lo != 0xFFFFFFFFu && hi != 0xFFFFFFFFu) {
                    v0 = __uint_as_float(lo);
                    v1 = __uint_as_float(hi);
                    break;
                }
            }
            int c = tid >> 4, m = (2 * tid) & 31;
            hstage[c * HSTR + m] = v0;
            hstage[c * HSTR + m + 1] = v1;
        }
        __syncthreads();                             // SYNC B
    }
}

// ---------------- feats: [S][12] = concat(hf, hb_rev) @ w_out.T + b_out ----------------
__global__ __launch_bounds__(256)
void feats_k(const float* __restrict__ hs, const float* __restrict__ w_out,
             const float* __restrict__ b_out, float* __restrict__ feats) {
    const int t = blockIdx.x, tid = threadIdx.x;
    float4 h4;
    if (tid < 128)
        h4 = *(const float4*)&hs[(size_t)t * HD + tid * 4];
    else
        h4 = *(const float4*)&hs[(size_t)S * HD + (size_t)(S - 1 - t) * HD + (tid - 128) * 4];
    float acc[NT];
#pragma unroll
    for (int tg = 0; tg < NT; ++tg) {
        float4 w4 = *(const float4*)&w_out[(size_t)tg * 1024 + tid * 4];
        acc[tg] = h4.x * w4.x + h4.y * w4.y + h4.z * w4.z + h4.w * w4.w;
    }
#pragma unroll
    for (int m = 1; m < 64; m <<= 1)
#pragma unroll
        for (int tg = 0; tg < NT; ++tg) acc[tg] += __shfl_xor(acc[tg], m);
    __shared__ float part[4][NT];
    if ((tid & 63) == 0) {
#pragma unroll
        for (int tg = 0; tg < NT; ++tg) part[tid >> 6][tg] = acc[tg];
    }
    __syncthreads();
    if (tid < NT)
        feats[(size_t)t * NT + tid] =
            part[0][tid] + part[1][tid] + part[2][tid] + part[3][tid] + b_out[tid];
}

// ---------------- CRF: forward algorithm + gold score, single block ----------------
__global__ __launch_bounds__(256, 1)
void crf_k(const float* __restrict__ feats, const int* __restrict__ gold,
           const float* __restrict__ trans, float* __restrict__ out) {
    extern __shared__ float sfeats[];      // S*NT floats = 96KB
    __shared__ float red[256];
    __shared__ float nprev[NT];
    __shared__ float tr[144];
    __shared__ float gold_sh;
    const int tid = threadIdx.x;
    for (int i = tid; i < S * NT / 4; i += 256)
        ((float4*)sfeats)[i] = ((const float4*)feats)[i];
    if (tid < 144) tr[tid] = trans[tid];
    __syncthreads();
    // gold score
    float gsum = 0.f;
    for (int t = tid; t < S; t += 256) {
        int a = gold[t];
        int b = t ? gold[t - 1] : 0;
        gsum += tr[a * NT + b] + sfeats[t * NT + a];
    }
    red[tid] = gsum;
    __syncthreads();
    for (int s = 128; s; s >>= 1) {
        if (tid < s) red[tid] += red[tid + s];
        __syncthreads();
    }
    if (tid == 0) gold_sh = red[0] + tr[1 * NT + gold[S - 1]];
    __syncthreads();
    // forward algorithm: i = tid/16 (next tag), j = tid%16 (prev tag)
    const int i = tid >> 4, j = tid & 15;
    const bool act = (tid < 192) && (j < NT);
    float tij = act ? tr[i * NT + j] : -3e38f;
    float prev = (j == 0) ? 0.f : -1e6f;
    for (int t = 0; t < S; ++t) {
        float v = act ? (prev + tij) : -3e38f;
        float mx = v;
        mx = fmaxf(mx, __shfl_xor(mx, 1));
        mx = fmaxf(mx, __shfl_xor(mx, 2));
        mx = fmaxf(mx, __shfl_xor(mx, 4));
        mx = fmaxf(mx, __shfl_xor(mx, 8));
        float e = __expf(v - mx);
        float ss = e;
        ss += __shfl_xor(ss, 1);
        ss += __shfl_xor(ss, 2);
        ss += __shfl_xor(ss, 4);
        ss += __shfl_xor(ss, 8);
        if (tid < 192 && j == 0) nprev[i] = mx + __logf(ss) + sfeats[t * NT + i];
        __syncthreads();
        prev = nprev[j < NT ? j : 0];
        __syncthreads();
    }
    if (tid < 64) {
        float v2 = (tid < NT) ? prev + tr[1 * NT + tid] : -3e38f;
        float mx = v2;
        mx = fmaxf(mx, __shfl_xor(mx, 1));
        mx = fmaxf(mx, __shfl_xor(mx, 2));
        mx = fmaxf(mx, __shfl_xor(mx, 4));
        mx = fmaxf(mx, __shfl_xor(mx, 8));
        float e = __expf(v2 - mx);
        float ss = e;
        ss += __shfl_xor(ss, 1);
        ss += __shfl_xor(ss, 2);
        ss += __shfl_xor(ss, 4);
        ss += __shfl_xor(ss, 8);
        if (tid == 0) out[0] = (mx + __logf(ss)) - gold_sh;
    }
}

extern "C" void kernel_launch(void* const* d_in, const int* in_sizes, int n_in,
                              void* d_out, int out_size, void* d_ws, size_t ws_size,
                              hipStream_t stream) {
    const int* sentence = (const int*)d_in[0];
    const int* gold = (const int*)d_in[1];
    const float* emb = (const float*)d_in[2];
    const float* wih_f = (const float*)d_in[3];
    const float* whh_f = (const float*)d_in[4];
    const float* b_f = (const float*)d_in[5];
    const float* wih_b = (const float*)d_in[6];
    const float* whh_b = (const float*)d_in[7];
    const float* b_b = (const float*)d_in[8];
    const float* w_out = (const float*)d_in[9];
    const float* b_out = (const float*)d_in[10];
    const float* trans = (const float*)d_in[11];
    const float* h0 = (const float*)d_in[12];
    const float* c0 = (const float*)d_in[13];
    float* out = (float*)d_out;

    char* ws = (char*)d_ws;
    const size_t XW_B = (size_t)2 * S * G4 * 2;          // 16,777,216
    const size_t HS_B = (size_t)2 * S * HD * 4;          // 8,388,608
    ushort_t* xw = (ushort_t*)ws;
    float* hs = (float*)(ws + XW_B);
    float* feats = (float*)(ws + XW_B + HS_B);

    // canary-fill h state buffer (0xFFFFFFFF, impossible output value)
    hipMemsetAsync(hs, 0xFF, HS_B, stream);

    dim3 gg(S / 64, G4 / 64, 2);
    xw_gemm<<<gg, 256, 0, stream>>>(sentence, emb, wih_f, b_f, wih_b, b_b, xw);

    lstm_rec<<<2 * NWGD, 256, 0, stream>>>(whh_f, whh_b, h0, c0, xw, hs);

    feats_k<<<S, 256, 0, stream>>>(hs, w_out, b_out, feats);

    const size_t CRF_LDS = (size_t)S * NT * 4;           // 98,304 B
    hipFuncSetAttribute((const void*)crf_k,
                        hipFuncAttributeMaxDynamicSharedMemorySize, (int)CRF_LDS);
    crf_k<<<1, 256, CRF_LDS, stream>>>(feats, gold, trans, out);
}